// Round 4
// baseline (124.874 us; speedup 1.0000x reference)
//
#include <hip/hip_runtime.h>
#include <math.h>

#define NBINS 80
#define NVERT 128
#define NRH 5
#define NDEG 6           // Taylor terms d=0..5; remainder ~1e-5 (<< f16 eps)

#define PSTR 136         // halves per P/M row; cols 0..127 data, 128..135 pad
#define VSTR 32          // halves per VT row
#define DSTR 80          // halves per desc row (per nt)
#define DI   1296        // halves per desc feature slab; 2592 B == 32 mod 128

#define OFF_VT 6800      // P/M: 25*136*2 = 6800 B at [0,6800)
#define VTSZ   3072      // VT: 48 rows x 32 halves (one a-half at a time)
#define OFF_GM 9872      // gm f16 x 128 = 256 B at [9872,10128)
#define SLICE  10400     // desc overlay [0,10368) after chain1 (P/VT/gm dead)

#define NSET_C 48        // C-matrix frag sets: 16 nt x 3 ks
#define NSET_W 60        // W frag sets: 4 i x 5 tiles x 3 ks
#define WS_BYTES ((NSET_C + NSET_W) * 64 * 8 * 2)

// Same-wave LDS ordering fences (replace the removed __syncthreads):
// - LDS_ORDER: compiler-level memory scheduling barrier (free) -- forces
//   program order of DS instructions; HW processes a wave's DS ops in order.
// - LDS_DRAIN: additionally drains lgkmcnt (belt-and-braces at the big
//   phase boundaries; a few cycles each, 3 per kernel).
#define LDS_ORDER() asm volatile("" ::: "memory")
#define LDS_DRAIN() asm volatile("s_waitcnt lgkmcnt(0)" ::: "memory")

typedef _Float16 half8 __attribute__((ext_vector_type(8)));
typedef float f32x4 __attribute__((ext_vector_type(4)));

// ---- prep: constant C-matrix frags + W frags in d_ws (unchanged, verified) ----
__global__ __launch_bounds__(64) void prep_frags(const float* __restrict__ Wc,
                                                 const float* __restrict__ sig_th,
                                                 _Float16* __restrict__ ws) {
    const int blk  = blockIdx.x;
    const int lane = threadIdx.x;
    constexpr float TWO_PI = 6.28318530717958647692f;
    constexpr float DLT    = TWO_PI / 16.0f;
    constexpr float LN2    = 0.69314718055994530942f;
    half8 h;
    if (blk < NSET_C) {
        constexpr float LOG2E = 1.44269504088896340736f;
        constexpr float EPSF  = 1e-5f;
        const float st = sig_th[0];
        const float Kt = -LOG2E / (st * st + EPSF);
        const int ks = blk % 3;
        const int nt = blk / 3;
        const int t  = lane & 15;
        const int q  = lane >> 4;
        #pragma unroll
        for (int j = 0; j < 8; ++j) {
            const int k = ks * 32 + q * 8 + j;     // 0..95
            const int a = k / NDEG;
            const int d = k % NDEG;
            const int m = ((a + nt) & 15) - t;
            const float s = fmaf((float)m, DLT, 0.5f * DLT);
            const float z = 2.0f * LN2 * Kt * s * (0.5f * DLT);
            float val = exp2f(Kt * s * s);
            for (int dd = 1; dd <= d; ++dd) val *= z / (float)dd;
            h[j] = (_Float16)val;
        }
    } else {
        const int e    = blk - NSET_C;
        const int ks   = e % 3;
        const int tile = (e / 3) % 5;
        const int i    = e / 15;
        const int cc   = tile * 16 + (lane & 15);
        const int bb0  = ks * 32 + (lane >> 4) * 8;
        #pragma unroll
        for (int j = 0; j < 8; ++j) {
            const int bb = bb0 + j;
            h[j] = (_Float16)((bb < NBINS) ? Wc[i * NBINS * NBINS + bb * NBINS + cc] : 0.0f);
        }
    }
    *(half8*)(ws + ((size_t)blk * 64 + lane) * 8) = h;
}

// WAVE-PER-SAMPLE (R2 restructure, R3 ordering fix): one 64-lane wave runs an
// entire sample's pipeline sequentially -- compaction (2x64 verts), chain1
// (both M-tiles x both col-halves, M0/M1[6] accumulators), chain2 (g=0..3),
// phase2 (i=0..3). ZERO barriers: all hazards are same-wave DS ordering
// (HW in-order per wave) made compiler-visible via LDS_ORDER/LDS_DRAIN
// fences at every former barrier site (R3 failure: without them, hipcc's AA
// reordered int4/f16 LDS ops across phases). LDS 10400 B/sample => ~16
// independent always-runnable samples per CU (vs 3.5 barrier-coupled).
template <int USEWS>
__global__ __launch_bounds__(64, 4) void masif_geo_conv(
    const float* __restrict__ rho_c,
    const float* __restrict__ th_c,
    const float* __restrict__ feat_g,
    const float* __restrict__ mask_g,
    const float* __restrict__ mu_rho,
    const float* __restrict__ sig_rho,
    const float* __restrict__ mu_th,
    const float* __restrict__ sig_th,
    const float* __restrict__ Wc,
    const float* __restrict__ bcv,
    const _Float16* __restrict__ ws,
    const int nsamp,
    float* __restrict__ out)
{
    const int lane = threadIdx.x;
    const int n    = blockIdx.x;          // grid == nsamp, 1 wave per block

    const int t  = lane & 15;
    const int kq = lane >> 4;

    __shared__ __align__(16) char s_raw[SLICE];
    _Float16* s_PM = (_Float16*)(s_raw);                 // P, then M
    _Float16* s_vt = (_Float16*)(s_raw + OFF_VT);        // VT (one col-half)
    _Float16* s_gm = (_Float16*)(s_raw + OFF_GM);
    _Float16* s_d  = (_Float16*)(s_raw);                 // desc overlay (late)

    constexpr float LOG2E   = 1.44269504088896340736f;
    constexpr float TWO_PI  = 6.28318530717958647692f;
    constexpr float DLT     = TWO_PI / 16.0f;
    constexpr float INV_DLT = 16.0f / TWO_PI;
    constexpr float EPSF    = 1e-5f;

    const float st = sig_th[0];
    const float Kt = -LOG2E / (st * st + EPSF);
    const float sr = sig_rho[0];
    const float Kr = -LOG2E / (sr * sr + EPSF);
    float mr[NRH];
    #pragma unroll
    for (int r = 0; r < NRH; ++r) mr[r] = mu_rho[r * 16];

    // ---- zero P incl. pads (425 int4, 64 lanes -> 7 rounds) ----
    #pragma unroll
    for (int x = 0; x < 7; ++x) {
        const int idx = x * 64 + lane;
        if (idx < 425) ((int4*)s_PM)[idx] = make_int4(0, 0, 0, 0);
    }
    LDS_ORDER();                                  // [1] zero before compaction

    // ---- compaction: 128 verts in 2 rounds of 64, wave-local ballot ----
    int nc = 0;
    #pragma unroll
    for (int h = 0; h < 2; ++h) {
        const int v     = h * 64 + lane;
        const float mv   = mask_g[n * NVERT + v];
        const float thv  = th_c[n * NVERT + v];
        const float rhov = rho_c[n * NVERT + v];
        const float4 f4  = *(const float4*)&feat_g[(n * NVERT + v) * 4];
        const bool act = (mv != 0.0f);
        const unsigned long long bal = __ballot(act);
        if (act) {
            const int pos = nc + (int)__popcll(bal & ((1ull << lane) - 1ull));
            int aa = (int)floorf(thv * INV_DLT);
            aa = aa > 15 ? 15 : (aa < 0 ? 0 : aa);
            const float rvp = thv - (float)aa * DLT - 0.5f * DLT;   // [-DLT/2, DLT/2)
            float R[NRH];
            #pragma unroll
            for (int r = 0; r < NRH; ++r) {
                const float dr = rhov - mr[r];
                R[r] = mv * exp2f(Kr * dr * dr);
            }
            const float fv[4] = {f4.x, f4.y, f4.z, f4.w};
            #pragma unroll
            for (int f = 0; f < 4; ++f) {
                #pragma unroll
                for (int r = 0; r < 4; ++r)
                    s_PM[(f * 4 + r) * PSTR + pos] = (_Float16)(fv[f] * R[r]);
                s_PM[(16 + f) * PSTR + pos] = (_Float16)(fv[f] * R[4]);
            }
            #pragma unroll
            for (int r = 0; r < NRH; ++r)
                s_PM[(20 + r) * PSTR + pos] = (_Float16)R[r];
            s_PM[(pos >> 3) * PSTR + 128 + (pos & 7)] = (_Float16)(rvp * (2.0f * INV_DLT));
            ((char*)s_PM)[(16 + (pos >> 4)) * 2 * PSTR + 256 + (pos & 15)] = (char)aa;
            s_gm[pos] = (_Float16)exp2f(Kt * rvp * rvp);
        }
        nc += (int)__popcll(bal);
    }
    LDS_DRAIN();                                  // [2] P/gm/tails complete

    // ---- chain 1: whole M (both tiles) in one wave. Per chunk: load both
    //      A-frags once, then for each col-half build VT (48 rows) and do
    //      6 MFMAs. M[tile][colblock] accumulators = 48 VGPR. ----
    f32x4 M0[6], M1[6];
    #pragma unroll
    for (int cb = 0; cb < 6; ++cb) {
        M0[cb] = (f32x4){0.f, 0.f, 0.f, 0.f};
        M1[cb] = (f32x4){0.f, 0.f, 0.f, 0.f};
    }
    const int nch = (nc + 31) >> 5;
    #pragma unroll 1
    for (int ch = 0; ch < nch; ++ch) {
        const half8 av0 = *(const half8*)(s_PM + t * PSTR + ch * 32 + kq * 8);
        const half8 av1 = *(const half8*)(s_PM + (16 + t) * PSTR + ch * 32 + kq * 8);
        #pragma unroll
        for (int chalf = 0; chalf < 2; ++chalf) {
            LDS_ORDER();                  // prev col-half's VT reads before re-zero
            #pragma unroll
            for (int x = 0; x < 3; ++x)
                ((int4*)s_vt)[x * 64 + lane] = make_int4(0, 0, 0, 0);
            LDS_ORDER();                  // zero before scatter-build
            {
                const int cl = lane >> 1;
                const int cg = ch * 32 + cl;
                if (cg < nc) {
                    const int a = (int)((char*)s_PM)[(16 + (cg >> 4)) * 2 * PSTR + 256 + (cg & 15)];
                    if ((a >> 3) == chalf) {
                        const float u = (float)s_PM[(cg >> 3) * PSTR + 128 + (cg & 7)];
                        const float g = (float)s_gm[cg];
                        const int  dh = (lane & 1) * 3;
                        float p0, p1, p2;
                        if (dh == 0) { p0 = 1.0f; p1 = u; p2 = u * u; }
                        else { const float u2 = u * u; p0 = u2 * u; p1 = u2 * u2; p2 = p0 * u2; }
                        const int bi = ((a - 8 * chalf) * NDEG + dh) * VSTR + cl;
                        s_vt[bi]            = (_Float16)(g * p0);
                        s_vt[bi + VSTR]     = (_Float16)(g * p1);
                        s_vt[bi + 2 * VSTR] = (_Float16)(g * p2);
                    }
                }
            }
            LDS_ORDER();                  // build before fragment reads
            // tile1 t>8 reads rows 25..31 (in-slice garbage -> unread M rows)
            #pragma unroll
            for (int lct = 0; lct < 3; ++lct) {
                const half8 b = *(const half8*)(s_vt + (lct * 16 + t) * VSTR + kq * 8);
                M0[chalf * 3 + lct] = __builtin_amdgcn_mfma_f32_16x16x32_f16(av0, b, M0[chalf * 3 + lct], 0, 0, 0);
                M1[chalf * 3 + lct] = __builtin_amdgcn_mfma_f32_16x16x32_f16(av1, b, M1[chalf * 3 + lct], 0, 0, 0);
            }
        }
    }
    LDS_ORDER();                                  // chain1 reads before M overwrite

    // ---- M (both tiles) -> LDS f16 A-layout. D: col=t, row=kq*4+reg ----
    #pragma unroll
    for (int cb = 0; cb < 6; ++cb) {
        const int md = cb * 16 + t;
        #pragma unroll
        for (int reg = 0; reg < 4; ++reg) {
            const int lr = kq * 4 + reg;
            s_PM[lr * PSTR + md] = (_Float16)M0[cb][reg];
            if (lr < 9)
                s_PM[(16 + lr) * PSTR + md] = (_Float16)M1[cb][reg];
        }
    }
    LDS_DRAIN();                                  // [3] M complete before A-frag reads

    // ---- chain2 A-frags -> regs (before desc overlays P/M) ----
    half8 A0[3], A1[3];
    #pragma unroll
    for (int ks = 0; ks < 3; ++ks) {
        A0[ks] = *(const half8*)(s_PM + t * PSTR + ks * 32 + kq * 8);
        A1[ks] = *(const half8*)(s_PM + (16 + t) * PSTR + ks * 32 + kq * 8);
    }
    LDS_ORDER();                                  // [4] A-frag reads before desc overlay

    // ---- chain 2: loop g = 0..3 sequentially; fused epilogue ----
    const half8* wsv = (const half8*)ws;
    #pragma unroll 1
    for (int g = 0; g < 4; ++g) {
        f32x4 C0g[4], C1g[4];
        #pragma unroll
        for (int j = 0; j < 4; ++j) {
            C0g[j] = (f32x4){0.f, 0.f, 0.f, 0.f};
            C1g[j] = (f32x4){0.f, 0.f, 0.f, 0.f};
        }
        #pragma unroll
        for (int j = 0; j < 4; ++j) {
            const int nt = g * 4 + j;
            half8 b0, b1, b2;
            if (USEWS) {
                b0 = wsv[(size_t)((nt * 3 + 0) * 64 + lane)];
                b1 = wsv[(size_t)((nt * 3 + 1) * 64 + lane)];
                b2 = wsv[(size_t)((nt * 3 + 2) * 64 + lane)];
            } else {
                #pragma unroll
                for (int ks = 0; ks < 3; ++ks) {
                    half8 bb;
                    #pragma unroll
                    for (int jj = 0; jj < 8; ++jj) {
                        const int k = ks * 32 + kq * 8 + jj;
                        const int a = k / NDEG, d = k % NDEG;
                        const int mm = ((a + nt) & 15) - t;
                        const float s = fmaf((float)mm, DLT, 0.5f * DLT);
                        const float z = 2.0f * 0.69314718055994530942f * Kt * s * (0.5f * DLT);
                        float val = exp2f(Kt * s * s);
                        for (int dd = 1; dd <= d; ++dd) val *= z / (float)dd;
                        bb[jj] = (_Float16)val;
                    }
                    if (ks == 0) b0 = bb; else if (ks == 1) b1 = bb; else b2 = bb;
                }
            }
            C0g[j] = __builtin_amdgcn_mfma_f32_16x16x32_f16(A0[0], b0, C0g[j], 0, 0, 0);
            C1g[j] = __builtin_amdgcn_mfma_f32_16x16x32_f16(A1[0], b0, C1g[j], 0, 0, 0);
            C0g[j] = __builtin_amdgcn_mfma_f32_16x16x32_f16(A0[1], b1, C0g[j], 0, 0, 0);
            C1g[j] = __builtin_amdgcn_mfma_f32_16x16x32_f16(A1[1], b1, C1g[j], 0, 0, 0);
            C0g[j] = __builtin_amdgcn_mfma_f32_16x16x32_f16(A0[2], b2, C0g[j], 0, 0, 0);
            C1g[j] = __builtin_amdgcn_mfma_f32_16x16x32_f16(A1[2], b2, C1g[j], 0, 0, 0);
        }
        // fused epilogue: desc = num/(den+eps) -> s_d[i][nt][bb]
        // DI=1296: kq-groups 8 banks apart on the b16 stores
        #pragma unroll
        for (int j = 0; j < 4; ++j) {
            const int nt = g * 4 + j;
            float den[5], inv[5];
            #pragma unroll
            for (int r = 0; r < 4; ++r) den[r] = __shfl(C1g[j][r], 16 + t);
            den[4] = __shfl(C1g[j][0], 32 + t);
            #pragma unroll
            for (int r = 0; r < NRH; ++r) {
                const float x = den[r] + EPSF;
                float vv = __builtin_amdgcn_rcpf(x);
                inv[r] = vv * (2.0f - x * vv);
            }
            #pragma unroll
            for (int reg = 0; reg < 4; ++reg)
                s_d[kq * DI + nt * DSTR + reg * 16 + t] =
                    (_Float16)(C0g[j][reg] * inv[reg]);
            if (kq == 0) {
                #pragma unroll
                for (int reg = 0; reg < 4; ++reg)
                    s_d[reg * DI + nt * DSTR + 64 + t] =
                        (_Float16)(C1g[j][reg] * inv[4]);
            }
        }
    }
    LDS_DRAIN();                                  // [5] desc complete before phase2 reads

    // ---- phase 2: loop i = 0..3 sequentially ----
    #pragma unroll 1
    for (int i = 0; i < 4; ++i) {
        f32x4 Cc[5];
        #pragma unroll
        for (int tl = 0; tl < 5; ++tl) Cc[tl] = (f32x4){0.f, 0.f, 0.f, 0.f};
        #pragma unroll
        for (int ks = 0; ks < 3; ++ks) {
            const half8 a = *(const half8*)(s_d + i * DI + t * DSTR + ks * 32 + kq * 8);
            #pragma unroll
            for (int tl = 0; tl < 5; ++tl) {
                half8 b;
                if (USEWS) {
                    b = wsv[(size_t)((NSET_C + (i * 5 + tl) * 3 + ks) * 64 + lane)];
                } else {
                    const int cc  = tl * 16 + t;
                    const int bb0 = ks * 32 + kq * 8;
                    #pragma unroll
                    for (int j = 0; j < 8; ++j) {
                        const int bb = bb0 + j;
                        b[j] = (_Float16)((bb < NBINS) ? Wc[i * NBINS * NBINS + bb * NBINS + cc] : 0.0f);
                    }
                }
                Cc[tl] = __builtin_amdgcn_mfma_f32_16x16x32_f16(a, b, Cc[tl], 0, 0, 0);
            }
        }
        #pragma unroll
        for (int tl = 0; tl < 5; ++tl) {
            float mx = fmaxf(fmaxf(Cc[tl][0], Cc[tl][1]), fmaxf(Cc[tl][2], Cc[tl][3]));
            mx = fmaxf(mx, __shfl_xor(mx, 16));
            mx = fmaxf(mx, __shfl_xor(mx, 32));
            if (lane < 16) {
                const int cc = tl * 16 + lane;
                out[(size_t)n * 320 + i * NBINS + cc] =
                    fmaxf(mx + bcv[i * NBINS + cc], 0.0f);
            }
        }
    }
}

extern "C" void kernel_launch(void* const* d_in, const int* in_sizes, int n_in,
                              void* d_out, int out_size, void* d_ws, size_t ws_size,
                              hipStream_t stream) {
    const float* rho   = (const float*)d_in[0];
    const float* theta = (const float*)d_in[1];
    const float* feat  = (const float*)d_in[2];
    const float* mask  = (const float*)d_in[3];
    const float* mu_r  = (const float*)d_in[4];
    const float* sg_r  = (const float*)d_in[5];
    const float* mu_t  = (const float*)d_in[6];
    const float* sg_t  = (const float*)d_in[7];
    const float* W     = (const float*)d_in[8];
    const float* bconv = (const float*)d_in[9];
    float* outp = (float*)d_out;

    const int nsamp = in_sizes[0] / NVERT;
    const int useWs = (ws_size >= (size_t)WS_BYTES) ? 1 : 0;
    _Float16* wsh = (_Float16*)d_ws;

    if (useWs) {
        prep_frags<<<NSET_C + NSET_W, 64, 0, stream>>>(W, sg_t, wsh);
        masif_geo_conv<1><<<nsamp, 64, 0, stream>>>(
            rho, theta, feat, mask, mu_r, sg_r, mu_t, sg_t, W, bconv,
            wsh, nsamp, outp);
    } else {
        masif_geo_conv<0><<<nsamp, 64, 0, stream>>>(
            rho, theta, feat, mask, mu_r, sg_r, mu_t, sg_t, W, bconv,
            wsh, nsamp, outp);
    }
}

// Round 5
// 115.052 us; speedup vs baseline: 1.0854x; 1.0854x over previous
//
#include <hip/hip_runtime.h>
#include <math.h>

#define NBINS 80
#define NVERT 128
#define NRH 5
#define NDEG 6           // Taylor terms d=0..5; remainder ~1e-5 (<< f16 eps)

#define PSTR 136         // halves per P/M row; cols 0..127 data, 128..135 pad
#define VSTR 32          // halves per VT row
#define DSTR 80          // halves per desc row (per nt)
#define DI   1280        // halves per desc feature slab (R4->R5: back from 1296;
                         // desc-write bank conflict proven off-critical-path in R2,
                         // and DI=1280 makes desc exactly 10240 B -> 8 WGs/CU)

#define OFF_VT 6800      // P/M: 25*136*2 = 6800 B at [0,6800)
#define VTSZ   3072      // VT: 48 rows x 32 halves (one a-half at a time)
#define OFF_GM 9872      // gm f16 x 128 = 256 B at [9872,10128)
#define SLICE  10240     // per-sample LDS slice; desc overlay [0,10240) after
                         // chain1 (P/VT/gm all dead). 2 slices = 20480 B/WG
                         // -> 163840/20480 = 8 WGs/CU = 16 waves/CU (2x R4)

#define NSET_C 48        // C-matrix frag sets: 16 nt x 3 ks
#define NSET_W 60        // W frag sets: 4 i x 5 tiles x 3 ks
#define WS_BYTES ((NSET_C + NSET_W) * 64 * 8 * 2)

// Same-wave LDS ordering fences (replace __syncthreads; R3 lesson):
// - LDS_ORDER: compiler-level memory scheduling barrier (free) -- forces
//   program order of DS instructions; HW processes a wave's DS ops in order.
// - LDS_DRAIN: additionally drains lgkmcnt at the big phase boundaries.
#define LDS_ORDER() asm volatile("" ::: "memory")
#define LDS_DRAIN() asm volatile("s_waitcnt lgkmcnt(0)" ::: "memory")

typedef _Float16 half8 __attribute__((ext_vector_type(8)));
typedef float f32x4 __attribute__((ext_vector_type(4)));

// ---- prep: constant C-matrix frags + W frags in d_ws (unchanged, verified) ----
__global__ __launch_bounds__(64) void prep_frags(const float* __restrict__ Wc,
                                                 const float* __restrict__ sig_th,
                                                 _Float16* __restrict__ ws) {
    const int blk  = blockIdx.x;
    const int lane = threadIdx.x;
    constexpr float TWO_PI = 6.28318530717958647692f;
    constexpr float DLT    = TWO_PI / 16.0f;
    constexpr float LN2    = 0.69314718055994530942f;
    half8 h;
    if (blk < NSET_C) {
        constexpr float LOG2E = 1.44269504088896340736f;
        constexpr float EPSF  = 1e-5f;
        const float st = sig_th[0];
        const float Kt = -LOG2E / (st * st + EPSF);
        const int ks = blk % 3;
        const int nt = blk / 3;
        const int t  = lane & 15;
        const int q  = lane >> 4;
        #pragma unroll
        for (int j = 0; j < 8; ++j) {
            const int k = ks * 32 + q * 8 + j;     // 0..95
            const int a = k / NDEG;
            const int d = k % NDEG;
            const int m = ((a + nt) & 15) - t;
            const float s = fmaf((float)m, DLT, 0.5f * DLT);
            const float z = 2.0f * LN2 * Kt * s * (0.5f * DLT);
            float val = exp2f(Kt * s * s);
            for (int dd = 1; dd <= d; ++dd) val *= z / (float)dd;
            h[j] = (_Float16)val;
        }
    } else {
        const int e    = blk - NSET_C;
        const int ks   = e % 3;
        const int tile = (e / 3) % 5;
        const int i    = e / 15;
        const int cc   = tile * 16 + (lane & 15);
        const int bb0  = ks * 32 + (lane >> 4) * 8;
        #pragma unroll
        for (int j = 0; j < 8; ++j) {
            const int bb = bb0 + j;
            h[j] = (_Float16)((bb < NBINS) ? Wc[i * NBINS * NBINS + bb * NBINS + cc] : 0.0f);
        }
    }
    *(half8*)(ws + ((size_t)blk * 64 + lane) * 8) = h;
}

// WAVE-PER-SAMPLE, 2 samples per 2-wave WG (R5 packing fix): each 64-lane
// wave runs one full sample pipeline in its own 10240 B LDS slice -- ZERO
// barriers, all hazards same-wave DS ordering via LDS_ORDER/LDS_DRAIN (R3
// lesson). R4 showed 1-wave WGs get only ~8 WGs/CU resident (25% occ) ->
// every pipe idle. 2-wave WGs at 20480 B give 8 WGs/CU = 16 waves/CU while
// keeping R4's ~2x-reduced total VALU work. Waves never wait on each other.
template <int USEWS>
__global__ __launch_bounds__(128, 4) void masif_geo_conv(
    const float* __restrict__ rho_c,
    const float* __restrict__ th_c,
    const float* __restrict__ feat_g,
    const float* __restrict__ mask_g,
    const float* __restrict__ mu_rho,
    const float* __restrict__ sig_rho,
    const float* __restrict__ mu_th,
    const float* __restrict__ sig_th,
    const float* __restrict__ Wc,
    const float* __restrict__ bcv,
    const _Float16* __restrict__ ws,
    const int nsamp,
    float* __restrict__ out)
{
    const int wave = threadIdx.x >> 6;
    const int lane = threadIdx.x & 63;
    const int n    = blockIdx.x * 2 + wave;   // one sample per wave

    __shared__ __align__(16) char s_raw[2 * SLICE];

    if (n >= nsamp) return;                   // safe: no barriers anywhere

    const int t  = lane & 15;
    const int kq = lane >> 4;

    char* s_base = s_raw + wave * SLICE;      // private per-wave slice
    _Float16* s_PM = (_Float16*)(s_base);                 // P, then M
    _Float16* s_vt = (_Float16*)(s_base + OFF_VT);        // VT (one col-half)
    _Float16* s_gm = (_Float16*)(s_base + OFF_GM);
    _Float16* s_d  = (_Float16*)(s_base);                 // desc overlay (late)

    constexpr float LOG2E   = 1.44269504088896340736f;
    constexpr float TWO_PI  = 6.28318530717958647692f;
    constexpr float DLT     = TWO_PI / 16.0f;
    constexpr float INV_DLT = 16.0f / TWO_PI;
    constexpr float EPSF    = 1e-5f;

    const float st = sig_th[0];
    const float Kt = -LOG2E / (st * st + EPSF);
    const float sr = sig_rho[0];
    const float Kr = -LOG2E / (sr * sr + EPSF);
    float mr[NRH];
    #pragma unroll
    for (int r = 0; r < NRH; ++r) mr[r] = mu_rho[r * 16];

    // ---- zero P incl. pads (425 int4, 64 lanes -> 7 rounds) ----
    #pragma unroll
    for (int x = 0; x < 7; ++x) {
        const int idx = x * 64 + lane;
        if (idx < 425) ((int4*)s_PM)[idx] = make_int4(0, 0, 0, 0);
    }
    LDS_ORDER();                                  // [1] zero before compaction

    // ---- compaction: 128 verts in 2 rounds of 64, wave-local ballot ----
    int nc = 0;
    #pragma unroll
    for (int h = 0; h < 2; ++h) {
        const int v     = h * 64 + lane;
        const float mv   = mask_g[n * NVERT + v];
        const float thv  = th_c[n * NVERT + v];
        const float rhov = rho_c[n * NVERT + v];
        const float4 f4  = *(const float4*)&feat_g[(n * NVERT + v) * 4];
        const bool act = (mv != 0.0f);
        const unsigned long long bal = __ballot(act);
        if (act) {
            const int pos = nc + (int)__popcll(bal & ((1ull << lane) - 1ull));
            int aa = (int)floorf(thv * INV_DLT);
            aa = aa > 15 ? 15 : (aa < 0 ? 0 : aa);
            const float rvp = thv - (float)aa * DLT - 0.5f * DLT;   // [-DLT/2, DLT/2)
            float R[NRH];
            #pragma unroll
            for (int r = 0; r < NRH; ++r) {
                const float dr = rhov - mr[r];
                R[r] = mv * exp2f(Kr * dr * dr);
            }
            const float fv[4] = {f4.x, f4.y, f4.z, f4.w};
            #pragma unroll
            for (int f = 0; f < 4; ++f) {
                #pragma unroll
                for (int r = 0; r < 4; ++r)
                    s_PM[(f * 4 + r) * PSTR + pos] = (_Float16)(fv[f] * R[r]);
                s_PM[(16 + f) * PSTR + pos] = (_Float16)(fv[f] * R[4]);
            }
            #pragma unroll
            for (int r = 0; r < NRH; ++r)
                s_PM[(20 + r) * PSTR + pos] = (_Float16)R[r];
            s_PM[(pos >> 3) * PSTR + 128 + (pos & 7)] = (_Float16)(rvp * (2.0f * INV_DLT));
            ((char*)s_PM)[(16 + (pos >> 4)) * 2 * PSTR + 256 + (pos & 15)] = (char)aa;
            s_gm[pos] = (_Float16)exp2f(Kt * rvp * rvp);
        }
        nc += (int)__popcll(bal);
    }
    LDS_DRAIN();                                  // [2] P/gm/tails complete

    // ---- chain 1: whole M (both tiles) in one wave. Per chunk: load both
    //      A-frags once, then for each col-half build VT (48 rows) and do
    //      6 MFMAs. M[tile][colblock] accumulators = 48 VGPR. ----
    f32x4 M0[6], M1[6];
    #pragma unroll
    for (int cb = 0; cb < 6; ++cb) {
        M0[cb] = (f32x4){0.f, 0.f, 0.f, 0.f};
        M1[cb] = (f32x4){0.f, 0.f, 0.f, 0.f};
    }
    const int nch = (nc + 31) >> 5;
    #pragma unroll 1
    for (int ch = 0; ch < nch; ++ch) {
        const half8 av0 = *(const half8*)(s_PM + t * PSTR + ch * 32 + kq * 8);
        const half8 av1 = *(const half8*)(s_PM + (16 + t) * PSTR + ch * 32 + kq * 8);
        #pragma unroll
        for (int chalf = 0; chalf < 2; ++chalf) {
            LDS_ORDER();                  // prev col-half's VT reads before re-zero
            #pragma unroll
            for (int x = 0; x < 3; ++x)
                ((int4*)s_vt)[x * 64 + lane] = make_int4(0, 0, 0, 0);
            LDS_ORDER();                  // zero before scatter-build
            {
                const int cl = lane >> 1;
                const int cg = ch * 32 + cl;
                if (cg < nc) {
                    const int a = (int)((char*)s_PM)[(16 + (cg >> 4)) * 2 * PSTR + 256 + (cg & 15)];
                    if ((a >> 3) == chalf) {
                        const float u = (float)s_PM[(cg >> 3) * PSTR + 128 + (cg & 7)];
                        const float g = (float)s_gm[cg];
                        const int  dh = (lane & 1) * 3;
                        float p0, p1, p2;
                        if (dh == 0) { p0 = 1.0f; p1 = u; p2 = u * u; }
                        else { const float u2 = u * u; p0 = u2 * u; p1 = u2 * u2; p2 = p0 * u2; }
                        const int bi = ((a - 8 * chalf) * NDEG + dh) * VSTR + cl;
                        s_vt[bi]            = (_Float16)(g * p0);
                        s_vt[bi + VSTR]     = (_Float16)(g * p1);
                        s_vt[bi + 2 * VSTR] = (_Float16)(g * p2);
                    }
                }
            }
            LDS_ORDER();                  // build before fragment reads
            // tile1 t>8 reads rows 25..31 (in-slice garbage -> unread M rows)
            #pragma unroll
            for (int lct = 0; lct < 3; ++lct) {
                const half8 b = *(const half8*)(s_vt + (lct * 16 + t) * VSTR + kq * 8);
                M0[chalf * 3 + lct] = __builtin_amdgcn_mfma_f32_16x16x32_f16(av0, b, M0[chalf * 3 + lct], 0, 0, 0);
                M1[chalf * 3 + lct] = __builtin_amdgcn_mfma_f32_16x16x32_f16(av1, b, M1[chalf * 3 + lct], 0, 0, 0);
            }
        }
    }
    LDS_ORDER();                                  // chain1 reads before M overwrite

    // ---- M (both tiles) -> LDS f16 A-layout. D: col=t, row=kq*4+reg ----
    #pragma unroll
    for (int cb = 0; cb < 6; ++cb) {
        const int md = cb * 16 + t;
        #pragma unroll
        for (int reg = 0; reg < 4; ++reg) {
            const int lr = kq * 4 + reg;
            s_PM[lr * PSTR + md] = (_Float16)M0[cb][reg];
            if (lr < 9)
                s_PM[(16 + lr) * PSTR + md] = (_Float16)M1[cb][reg];
        }
    }
    LDS_DRAIN();                                  // [3] M complete before A-frag reads

    // ---- chain2 A-frags -> regs (before desc overlays P/M) ----
    half8 A0[3], A1[3];
    #pragma unroll
    for (int ks = 0; ks < 3; ++ks) {
        A0[ks] = *(const half8*)(s_PM + t * PSTR + ks * 32 + kq * 8);
        A1[ks] = *(const half8*)(s_PM + (16 + t) * PSTR + ks * 32 + kq * 8);
    }
    LDS_ORDER();                                  // [4] A-frag reads before desc overlay

    // ---- chain 2: loop g = 0..3 sequentially; fused epilogue ----
    const half8* wsv = (const half8*)ws;
    #pragma unroll 1
    for (int g = 0; g < 4; ++g) {
        f32x4 C0g[4], C1g[4];
        #pragma unroll
        for (int j = 0; j < 4; ++j) {
            C0g[j] = (f32x4){0.f, 0.f, 0.f, 0.f};
            C1g[j] = (f32x4){0.f, 0.f, 0.f, 0.f};
        }
        #pragma unroll
        for (int j = 0; j < 4; ++j) {
            const int nt = g * 4 + j;
            half8 b0, b1, b2;
            if (USEWS) {
                b0 = wsv[(size_t)((nt * 3 + 0) * 64 + lane)];
                b1 = wsv[(size_t)((nt * 3 + 1) * 64 + lane)];
                b2 = wsv[(size_t)((nt * 3 + 2) * 64 + lane)];
            } else {
                #pragma unroll
                for (int ks = 0; ks < 3; ++ks) {
                    half8 bb;
                    #pragma unroll
                    for (int jj = 0; jj < 8; ++jj) {
                        const int k = ks * 32 + kq * 8 + jj;
                        const int a = k / NDEG, d = k % NDEG;
                        const int mm = ((a + nt) & 15) - t;
                        const float s = fmaf((float)mm, DLT, 0.5f * DLT);
                        const float z = 2.0f * 0.69314718055994530942f * Kt * s * (0.5f * DLT);
                        float val = exp2f(Kt * s * s);
                        for (int dd = 1; dd <= d; ++dd) val *= z / (float)dd;
                        bb[jj] = (_Float16)val;
                    }
                    if (ks == 0) b0 = bb; else if (ks == 1) b1 = bb; else b2 = bb;
                }
            }
            C0g[j] = __builtin_amdgcn_mfma_f32_16x16x32_f16(A0[0], b0, C0g[j], 0, 0, 0);
            C1g[j] = __builtin_amdgcn_mfma_f32_16x16x32_f16(A1[0], b0, C1g[j], 0, 0, 0);
            C0g[j] = __builtin_amdgcn_mfma_f32_16x16x32_f16(A0[1], b1, C0g[j], 0, 0, 0);
            C1g[j] = __builtin_amdgcn_mfma_f32_16x16x32_f16(A1[1], b1, C1g[j], 0, 0, 0);
            C0g[j] = __builtin_amdgcn_mfma_f32_16x16x32_f16(A0[2], b2, C0g[j], 0, 0, 0);
            C1g[j] = __builtin_amdgcn_mfma_f32_16x16x32_f16(A1[2], b2, C1g[j], 0, 0, 0);
        }
        // fused epilogue: desc = num/(den+eps) -> s_d[i][nt][bb]
        #pragma unroll
        for (int j = 0; j < 4; ++j) {
            const int nt = g * 4 + j;
            float den[5], inv[5];
            #pragma unroll
            for (int r = 0; r < 4; ++r) den[r] = __shfl(C1g[j][r], 16 + t);
            den[4] = __shfl(C1g[j][0], 32 + t);
            #pragma unroll
            for (int r = 0; r < NRH; ++r) {
                const float x = den[r] + EPSF;
                float vv = __builtin_amdgcn_rcpf(x);
                inv[r] = vv * (2.0f - x * vv);
            }
            #pragma unroll
            for (int reg = 0; reg < 4; ++reg)
                s_d[kq * DI + nt * DSTR + reg * 16 + t] =
                    (_Float16)(C0g[j][reg] * inv[reg]);
            if (kq == 0) {
                #pragma unroll
                for (int reg = 0; reg < 4; ++reg)
                    s_d[reg * DI + nt * DSTR + 64 + t] =
                        (_Float16)(C1g[j][reg] * inv[4]);
            }
        }
    }
    LDS_DRAIN();                                  // [5] desc complete before phase2 reads

    // ---- phase 2: loop i = 0..3 sequentially ----
    #pragma unroll 1
    for (int i = 0; i < 4; ++i) {
        f32x4 Cc[5];
        #pragma unroll
        for (int tl = 0; tl < 5; ++tl) Cc[tl] = (f32x4){0.f, 0.f, 0.f, 0.f};
        #pragma unroll
        for (int ks = 0; ks < 3; ++ks) {
            const half8 a = *(const half8*)(s_d + i * DI + t * DSTR + ks * 32 + kq * 8);
            #pragma unroll
            for (int tl = 0; tl < 5; ++tl) {
                half8 b;
                if (USEWS) {
                    b = wsv[(size_t)((NSET_C + (i * 5 + tl) * 3 + ks) * 64 + lane)];
                } else {
                    const int cc  = tl * 16 + t;
                    const int bb0 = ks * 32 + kq * 8;
                    #pragma unroll
                    for (int j = 0; j < 8; ++j) {
                        const int bb = bb0 + j;
                        b[j] = (_Float16)((bb < NBINS) ? Wc[i * NBINS * NBINS + bb * NBINS + cc] : 0.0f);
                    }
                }
                Cc[tl] = __builtin_amdgcn_mfma_f32_16x16x32_f16(a, b, Cc[tl], 0, 0, 0);
            }
        }
        #pragma unroll
        for (int tl = 0; tl < 5; ++tl) {
            float mx = fmaxf(fmaxf(Cc[tl][0], Cc[tl][1]), fmaxf(Cc[tl][2], Cc[tl][3]));
            mx = fmaxf(mx, __shfl_xor(mx, 16));
            mx = fmaxf(mx, __shfl_xor(mx, 32));
            if (lane < 16) {
                const int cc = tl * 16 + lane;
                out[(size_t)n * 320 + i * NBINS + cc] =
                    fmaxf(mx + bcv[i * NBINS + cc], 0.0f);
            }
        }
    }
}

extern "C" void kernel_launch(void* const* d_in, const int* in_sizes, int n_in,
                              void* d_out, int out_size, void* d_ws, size_t ws_size,
                              hipStream_t stream) {
    const float* rho   = (const float*)d_in[0];
    const float* theta = (const float*)d_in[1];
    const float* feat  = (const float*)d_in[2];
    const float* mask  = (const float*)d_in[3];
    const float* mu_r  = (const float*)d_in[4];
    const float* sg_r  = (const float*)d_in[5];
    const float* mu_t  = (const float*)d_in[6];
    const float* sg_t  = (const float*)d_in[7];
    const float* W     = (const float*)d_in[8];
    const float* bconv = (const float*)d_in[9];
    float* outp = (float*)d_out;

    const int nsamp = in_sizes[0] / NVERT;
    const int ngrid = (nsamp + 1) / 2;        // 2 samples per WG
    const int useWs = (ws_size >= (size_t)WS_BYTES) ? 1 : 0;
    _Float16* wsh = (_Float16*)d_ws;

    if (useWs) {
        prep_frags<<<NSET_C + NSET_W, 64, 0, stream>>>(W, sg_t, wsh);
        masif_geo_conv<1><<<ngrid, 128, 0, stream>>>(
            rho, theta, feat, mask, mu_r, sg_r, mu_t, sg_t, W, bconv,
            wsh, nsamp, outp);
    } else {
        masif_geo_conv<0><<<ngrid, 128, 0, stream>>>(
            rho, theta, feat, mask, mu_r, sg_r, mu_t, sg_t, W, bconv,
            wsh, nsamp, outp);
    }
}

// Round 6
// 114.488 us; speedup vs baseline: 1.0907x; 1.0049x over previous
//
#include <hip/hip_runtime.h>
#include <math.h>

#define NBINS 80
#define NVERT 128
#define NRH 5
#define NDEG 6           // Taylor terms d=0..5; remainder ~1e-5 (<< f16 eps)

#define PSTR 136         // halves per P/M row; cols 0..127 data, 128..135 pad
#define VSTR 32          // halves per VT row
#define DSTR 80          // halves per desc row (per nt)
#define DI   1280        // halves per desc feature slab (desc = exactly 10240 B)

#define OFF_VT 6800      // P/M: 25*136*2 = 6800 B at [0,6800)
#define VTSZ   3072      // VT: 48 rows x 32 halves (one a-half at a time)
#define OFF_GM 9872      // gm f16 x 128 = 256 B at [9872,10128)
#define SLICE  10240     // per-sample LDS slice; desc overlay [0,10240) after
                         // chain1. 2 slices = 20480 B/WG = exact 512-granule
                         // -> 8 WGs/CU = 16 waves/CU

#define NSET_C 48        // C-matrix frag sets: 16 nt x 3 ks
#define NSET_W 60        // W frag sets: 4 i x 5 tiles x 3 ks
#define WS_BYTES ((NSET_C + NSET_W) * 64 * 8 * 2)

// Same-wave LDS ordering fences (replace __syncthreads; R3 lesson):
// - LDS_ORDER: compiler-level memory scheduling barrier (free) -- forces
//   program order of DS instructions; HW processes a wave's DS ops in order.
// - LDS_DRAIN: additionally drains lgkmcnt at the big phase boundaries.
#define LDS_ORDER() asm volatile("" ::: "memory")
#define LDS_DRAIN() asm volatile("s_waitcnt lgkmcnt(0)" ::: "memory")

typedef _Float16 half8 __attribute__((ext_vector_type(8)));
typedef float f32x4 __attribute__((ext_vector_type(4)));

// ---- prep: constant C-matrix frags + W frags in d_ws (unchanged, verified) ----
__global__ __launch_bounds__(64) void prep_frags(const float* __restrict__ Wc,
                                                 const float* __restrict__ sig_th,
                                                 _Float16* __restrict__ ws) {
    const int blk  = blockIdx.x;
    const int lane = threadIdx.x;
    constexpr float TWO_PI = 6.28318530717958647692f;
    constexpr float DLT    = TWO_PI / 16.0f;
    constexpr float LN2    = 0.69314718055994530942f;
    half8 h;
    if (blk < NSET_C) {
        constexpr float LOG2E = 1.44269504088896340736f;
        constexpr float EPSF  = 1e-5f;
        const float st = sig_th[0];
        const float Kt = -LOG2E / (st * st + EPSF);
        const int ks = blk % 3;
        const int nt = blk / 3;
        const int t  = lane & 15;
        const int q  = lane >> 4;
        #pragma unroll
        for (int j = 0; j < 8; ++j) {
            const int k = ks * 32 + q * 8 + j;     // 0..95
            const int a = k / NDEG;
            const int d = k % NDEG;
            const int m = ((a + nt) & 15) - t;
            const float s = fmaf((float)m, DLT, 0.5f * DLT);
            const float z = 2.0f * LN2 * Kt * s * (0.5f * DLT);
            float val = exp2f(Kt * s * s);
            for (int dd = 1; dd <= d; ++dd) val *= z / (float)dd;
            h[j] = (_Float16)val;
        }
    } else {
        const int e    = blk - NSET_C;
        const int ks   = e % 3;
        const int tile = (e / 3) % 5;
        const int i    = e / 15;
        const int cc   = tile * 16 + (lane & 15);
        const int bb0  = ks * 32 + (lane >> 4) * 8;
        #pragma unroll
        for (int j = 0; j < 8; ++j) {
            const int bb = bb0 + j;
            h[j] = (_Float16)((bb < NBINS) ? Wc[i * NBINS * NBINS + bb * NBINS + cc] : 0.0f);
        }
    }
    *(half8*)(ws + ((size_t)blk * 64 + lane) * 8) = h;
}

// WAVE-PER-SAMPLE, 2 samples per 2-wave WG (R5 packing, R6 latency cuts):
// each 64-lane wave runs one full sample pipeline in its own 10240 B LDS
// slice -- ZERO barriers, all hazards same-wave DS ordering via
// LDS_ORDER/LDS_DRAIN (R3 lesson). 8 WGs/CU = 16 waves/CU. R6: (1) chain1
// reads a/u/g ONCE per chunk (was once per chalf) -- removes a redundant
// serialized LDS round trip; (2) chain2 g-loop and phase2 i-loop unroll 2 --
// R5's VGPR=52 proved the compiler serialized load->wait->MFMA per
// iteration; exposing 2 iterations lets the global ws loads pipeline under
// the previous iteration's MFMAs+epilogue (budget <=128 VGPR @ 4 waves/EU).
template <int USEWS>
__global__ __launch_bounds__(128, 4) void masif_geo_conv(
    const float* __restrict__ rho_c,
    const float* __restrict__ th_c,
    const float* __restrict__ feat_g,
    const float* __restrict__ mask_g,
    const float* __restrict__ mu_rho,
    const float* __restrict__ sig_rho,
    const float* __restrict__ mu_th,
    const float* __restrict__ sig_th,
    const float* __restrict__ Wc,
    const float* __restrict__ bcv,
    const _Float16* __restrict__ ws,
    const int nsamp,
    float* __restrict__ out)
{
    const int wave = threadIdx.x >> 6;
    const int lane = threadIdx.x & 63;
    const int n    = blockIdx.x * 2 + wave;   // one sample per wave

    __shared__ __align__(16) char s_raw[2 * SLICE];

    if (n >= nsamp) return;                   // safe: no barriers anywhere

    const int t  = lane & 15;
    const int kq = lane >> 4;

    char* s_base = s_raw + wave * SLICE;      // private per-wave slice
    _Float16* s_PM = (_Float16*)(s_base);                 // P, then M
    _Float16* s_vt = (_Float16*)(s_base + OFF_VT);        // VT (one col-half)
    _Float16* s_gm = (_Float16*)(s_base + OFF_GM);
    _Float16* s_d  = (_Float16*)(s_base);                 // desc overlay (late)

    constexpr float LOG2E   = 1.44269504088896340736f;
    constexpr float TWO_PI  = 6.28318530717958647692f;
    constexpr float DLT     = TWO_PI / 16.0f;
    constexpr float INV_DLT = 16.0f / TWO_PI;
    constexpr float EPSF    = 1e-5f;

    const float st = sig_th[0];
    const float Kt = -LOG2E / (st * st + EPSF);
    const float sr = sig_rho[0];
    const float Kr = -LOG2E / (sr * sr + EPSF);
    float mr[NRH];
    #pragma unroll
    for (int r = 0; r < NRH; ++r) mr[r] = mu_rho[r * 16];

    // ---- zero P incl. pads (425 int4, 64 lanes -> 7 rounds) ----
    #pragma unroll
    for (int x = 0; x < 7; ++x) {
        const int idx = x * 64 + lane;
        if (idx < 425) ((int4*)s_PM)[idx] = make_int4(0, 0, 0, 0);
    }
    LDS_ORDER();                                  // [1] zero before compaction

    // ---- compaction: 128 verts in 2 rounds of 64, wave-local ballot ----
    int nc = 0;
    #pragma unroll
    for (int h = 0; h < 2; ++h) {
        const int v     = h * 64 + lane;
        const float mv   = mask_g[n * NVERT + v];
        const float thv  = th_c[n * NVERT + v];
        const float rhov = rho_c[n * NVERT + v];
        const float4 f4  = *(const float4*)&feat_g[(n * NVERT + v) * 4];
        const bool act = (mv != 0.0f);
        const unsigned long long bal = __ballot(act);
        if (act) {
            const int pos = nc + (int)__popcll(bal & ((1ull << lane) - 1ull));
            int aa = (int)floorf(thv * INV_DLT);
            aa = aa > 15 ? 15 : (aa < 0 ? 0 : aa);
            const float rvp = thv - (float)aa * DLT - 0.5f * DLT;   // [-DLT/2, DLT/2)
            float R[NRH];
            #pragma unroll
            for (int r = 0; r < NRH; ++r) {
                const float dr = rhov - mr[r];
                R[r] = mv * exp2f(Kr * dr * dr);
            }
            const float fv[4] = {f4.x, f4.y, f4.z, f4.w};
            #pragma unroll
            for (int f = 0; f < 4; ++f) {
                #pragma unroll
                for (int r = 0; r < 4; ++r)
                    s_PM[(f * 4 + r) * PSTR + pos] = (_Float16)(fv[f] * R[r]);
                s_PM[(16 + f) * PSTR + pos] = (_Float16)(fv[f] * R[4]);
            }
            #pragma unroll
            for (int r = 0; r < NRH; ++r)
                s_PM[(20 + r) * PSTR + pos] = (_Float16)R[r];
            s_PM[(pos >> 3) * PSTR + 128 + (pos & 7)] = (_Float16)(rvp * (2.0f * INV_DLT));
            ((char*)s_PM)[(16 + (pos >> 4)) * 2 * PSTR + 256 + (pos & 15)] = (char)aa;
            s_gm[pos] = (_Float16)exp2f(Kt * rvp * rvp);
        }
        nc += (int)__popcll(bal);
    }
    LDS_DRAIN();                                  // [2] P/gm/tails complete

    // ---- chain 1: whole M (both tiles) in one wave. R6: a/u/g read ONCE
    //      per chunk (before the chalf loop); all six Taylor powers derive
    //      from registers. Per chalf: zero VT, guarded 3-store, 3 b128
    //      reads, 6 MFMAs. M[tile][colblock] accumulators = 48 VGPR. ----
    f32x4 M0[6], M1[6];
    #pragma unroll
    for (int cb = 0; cb < 6; ++cb) {
        M0[cb] = (f32x4){0.f, 0.f, 0.f, 0.f};
        M1[cb] = (f32x4){0.f, 0.f, 0.f, 0.f};
    }
    const int nch = (nc + 31) >> 5;
    #pragma unroll 1
    for (int ch = 0; ch < nch; ++ch) {
        const half8 av0 = *(const half8*)(s_PM + t * PSTR + ch * 32 + kq * 8);
        const half8 av1 = *(const half8*)(s_PM + (16 + t) * PSTR + ch * 32 + kq * 8);
        // per-chunk vert data (one LDS round trip, reused by both chalves)
        const int cl = lane >> 1;
        const int cg = ch * 32 + cl;
        const bool valid = (cg < nc);
        const int   a  = (int)((char*)s_PM)[(16 + (cg >> 4)) * 2 * PSTR + 256 + (cg & 15)];
        const float u  = (float)s_PM[(cg >> 3) * PSTR + 128 + (cg & 7)];
        const float g  = (float)s_gm[cg];
        const int  dh = (lane & 1) * 3;
        float p0, p1, p2;
        if (dh == 0) { p0 = 1.0f; p1 = u; p2 = u * u; }
        else { const float u2 = u * u; p0 = u2 * u; p1 = u2 * u2; p2 = p0 * u2; }
        const _Float16 w0 = (_Float16)(g * p0);
        const _Float16 w1 = (_Float16)(g * p1);
        const _Float16 w2 = (_Float16)(g * p2);
        const int ah   = a >> 3;                 // col-half this vert belongs to
        const int bi0  = ((a & 7) * NDEG + dh) * VSTR + cl;
        #pragma unroll
        for (int chalf = 0; chalf < 2; ++chalf) {
            LDS_ORDER();                  // prev col-half's VT reads before re-zero
            #pragma unroll
            for (int x = 0; x < 3; ++x)
                ((int4*)s_vt)[x * 64 + lane] = make_int4(0, 0, 0, 0);
            LDS_ORDER();                  // zero before scatter-build
            if (valid && ah == chalf) {
                s_vt[bi0]            = w0;
                s_vt[bi0 + VSTR]     = w1;
                s_vt[bi0 + 2 * VSTR] = w2;
            }
            LDS_ORDER();                  // build before fragment reads
            // tile1 t>8 reads rows 25..31 (in-slice garbage -> unread M rows)
            #pragma unroll
            for (int lct = 0; lct < 3; ++lct) {
                const half8 b = *(const half8*)(s_vt + (lct * 16 + t) * VSTR + kq * 8);
                M0[chalf * 3 + lct] = __builtin_amdgcn_mfma_f32_16x16x32_f16(av0, b, M0[chalf * 3 + lct], 0, 0, 0);
                M1[chalf * 3 + lct] = __builtin_amdgcn_mfma_f32_16x16x32_f16(av1, b, M1[chalf * 3 + lct], 0, 0, 0);
            }
        }
    }
    LDS_ORDER();                                  // chain1 reads before M overwrite

    // ---- M (both tiles) -> LDS f16 A-layout. D: col=t, row=kq*4+reg ----
    #pragma unroll
    for (int cb = 0; cb < 6; ++cb) {
        const int md = cb * 16 + t;
        #pragma unroll
        for (int reg = 0; reg < 4; ++reg) {
            const int lr = kq * 4 + reg;
            s_PM[lr * PSTR + md] = (_Float16)M0[cb][reg];
            if (lr < 9)
                s_PM[(16 + lr) * PSTR + md] = (_Float16)M1[cb][reg];
        }
    }
    LDS_DRAIN();                                  // [3] M complete before A-frag reads

    // ---- chain2 A-frags -> regs (before desc overlays P/M) ----
    half8 A0[3], A1[3];
    #pragma unroll
    for (int ks = 0; ks < 3; ++ks) {
        A0[ks] = *(const half8*)(s_PM + t * PSTR + ks * 32 + kq * 8);
        A1[ks] = *(const half8*)(s_PM + (16 + t) * PSTR + ks * 32 + kq * 8);
    }
    LDS_ORDER();                                  // [4] A-frag reads before desc overlay

    // ---- chain 2: g-loop, unroll 2 so next g's ws loads pipeline under
    //      this g's MFMAs+epilogue; fused epilogue ----
    const half8* wsv = (const half8*)ws;
    #pragma unroll 2
    for (int g = 0; g < 4; ++g) {
        f32x4 C0g[4], C1g[4];
        #pragma unroll
        for (int j = 0; j < 4; ++j) {
            C0g[j] = (f32x4){0.f, 0.f, 0.f, 0.f};
            C1g[j] = (f32x4){0.f, 0.f, 0.f, 0.f};
        }
        #pragma unroll
        for (int j = 0; j < 4; ++j) {
            const int nt = g * 4 + j;
            half8 b0, b1, b2;
            if (USEWS) {
                b0 = wsv[(size_t)((nt * 3 + 0) * 64 + lane)];
                b1 = wsv[(size_t)((nt * 3 + 1) * 64 + lane)];
                b2 = wsv[(size_t)((nt * 3 + 2) * 64 + lane)];
            } else {
                #pragma unroll
                for (int ks = 0; ks < 3; ++ks) {
                    half8 bb;
                    #pragma unroll
                    for (int jj = 0; jj < 8; ++jj) {
                        const int k = ks * 32 + kq * 8 + jj;
                        const int a = k / NDEG, d = k % NDEG;
                        const int mm = ((a + nt) & 15) - t;
                        const float s = fmaf((float)mm, DLT, 0.5f * DLT);
                        const float z = 2.0f * 0.69314718055994530942f * Kt * s * (0.5f * DLT);
                        float val = exp2f(Kt * s * s);
                        for (int dd = 1; dd <= d; ++dd) val *= z / (float)dd;
                        bb[jj] = (_Float16)val;
                    }
                    if (ks == 0) b0 = bb; else if (ks == 1) b1 = bb; else b2 = bb;
                }
            }
            C0g[j] = __builtin_amdgcn_mfma_f32_16x16x32_f16(A0[0], b0, C0g[j], 0, 0, 0);
            C1g[j] = __builtin_amdgcn_mfma_f32_16x16x32_f16(A1[0], b0, C1g[j], 0, 0, 0);
            C0g[j] = __builtin_amdgcn_mfma_f32_16x16x32_f16(A0[1], b1, C0g[j], 0, 0, 0);
            C1g[j] = __builtin_amdgcn_mfma_f32_16x16x32_f16(A1[1], b1, C1g[j], 0, 0, 0);
            C0g[j] = __builtin_amdgcn_mfma_f32_16x16x32_f16(A0[2], b2, C0g[j], 0, 0, 0);
            C1g[j] = __builtin_amdgcn_mfma_f32_16x16x32_f16(A1[2], b2, C1g[j], 0, 0, 0);
        }
        // fused epilogue: desc = num/(den+eps) -> s_d[i][nt][bb]
        #pragma unroll
        for (int j = 0; j < 4; ++j) {
            const int nt = g * 4 + j;
            float den[5], inv[5];
            #pragma unroll
            for (int r = 0; r < 4; ++r) den[r] = __shfl(C1g[j][r], 16 + t);
            den[4] = __shfl(C1g[j][0], 32 + t);
            #pragma unroll
            for (int r = 0; r < NRH; ++r) {
                const float x = den[r] + EPSF;
                float vv = __builtin_amdgcn_rcpf(x);
                inv[r] = vv * (2.0f - x * vv);
            }
            #pragma unroll
            for (int reg = 0; reg < 4; ++reg)
                s_d[kq * DI + nt * DSTR + reg * 16 + t] =
                    (_Float16)(C0g[j][reg] * inv[reg]);
            if (kq == 0) {
                #pragma unroll
                for (int reg = 0; reg < 4; ++reg)
                    s_d[reg * DI + nt * DSTR + 64 + t] =
                        (_Float16)(C1g[j][reg] * inv[4]);
            }
        }
    }
    LDS_DRAIN();                                  // [5] desc complete before phase2 reads

    // ---- phase 2: i-loop, unroll 2 (pipeline W/desc loads across i) ----
    #pragma unroll 2
    for (int i = 0; i < 4; ++i) {
        f32x4 Cc[5];
        #pragma unroll
        for (int tl = 0; tl < 5; ++tl) Cc[tl] = (f32x4){0.f, 0.f, 0.f, 0.f};
        #pragma unroll
        for (int ks = 0; ks < 3; ++ks) {
            const half8 a = *(const half8*)(s_d + i * DI + t * DSTR + ks * 32 + kq * 8);
            #pragma unroll
            for (int tl = 0; tl < 5; ++tl) {
                half8 b;
                if (USEWS) {
                    b = wsv[(size_t)((NSET_C + (i * 5 + tl) * 3 + ks) * 64 + lane)];
                } else {
                    const int cc  = tl * 16 + t;
                    const int bb0 = ks * 32 + kq * 8;
                    #pragma unroll
                    for (int j = 0; j < 8; ++j) {
                        const int bb = bb0 + j;
                        b[j] = (_Float16)((bb < NBINS) ? Wc[i * NBINS * NBINS + bb * NBINS + cc] : 0.0f);
                    }
                }
                Cc[tl] = __builtin_amdgcn_mfma_f32_16x16x32_f16(a, b, Cc[tl], 0, 0, 0);
            }
        }
        #pragma unroll
        for (int tl = 0; tl < 5; ++tl) {
            float mx = fmaxf(fmaxf(Cc[tl][0], Cc[tl][1]), fmaxf(Cc[tl][2], Cc[tl][3]));
            mx = fmaxf(mx, __shfl_xor(mx, 16));
            mx = fmaxf(mx, __shfl_xor(mx, 32));
            if (lane < 16) {
                const int cc = tl * 16 + lane;
                out[(size_t)n * 320 + i * NBINS + cc] =
                    fmaxf(mx + bcv[i * NBINS + cc], 0.0f);
            }
        }
    }
}

extern "C" void kernel_launch(void* const* d_in, const int* in_sizes, int n_in,
                              void* d_out, int out_size, void* d_ws, size_t ws_size,
                              hipStream_t stream) {
    const float* rho   = (const float*)d_in[0];
    const float* theta = (const float*)d_in[1];
    const float* feat  = (const float*)d_in[2];
    const float* mask  = (const float*)d_in[3];
    const float* mu_r  = (const float*)d_in[4];
    const float* sg_r  = (const float*)d_in[5];
    const float* mu_t  = (const float*)d_in[6];
    const float* sg_t  = (const float*)d_in[7];
    const float* W     = (const float*)d_in[8];
    const float* bconv = (const float*)d_in[9];
    float* outp = (float*)d_out;

    const int nsamp = in_sizes[0] / NVERT;
    const int ngrid = (nsamp + 1) / 2;        // 2 samples per WG
    const int useWs = (ws_size >= (size_t)WS_BYTES) ? 1 : 0;
    _Float16* wsh = (_Float16*)d_ws;

    if (useWs) {
        prep_frags<<<NSET_C + NSET_W, 64, 0, stream>>>(W, sg_t, wsh);
        masif_geo_conv<1><<<ngrid, 128, 0, stream>>>(
            rho, theta, feat, mask, mu_r, sg_r, mu_t, sg_t, W, bconv,
            wsh, nsamp, outp);
    } else {
        masif_geo_conv<0><<<ngrid, 128, 0, stream>>>(
            rho, theta, feat, mask, mu_r, sg_r, mu_t, sg_t, W, bconv,
            wsh, nsamp, outp);
    }
}

// Round 7
// 111.279 us; speedup vs baseline: 1.1222x; 1.0288x over previous
//
#include <hip/hip_runtime.h>
#include <math.h>

#define NBINS 80
#define NVERT 128
#define NRH 5
#define NDEG 6           // Taylor terms d=0..5; remainder ~1e-5 (<< f16 eps)

#define PSTR 136         // halves per P/M row; cols 0..127 data, 128..135 pad
#define VSTR 32          // halves per VT row
#define DSTR 80          // halves per desc row (per nt)
#define DI   1280        // halves per desc feature slab (desc = exactly 10240 B)

#define OFF_VT 6800      // P/M: 25*136*2 = 6800 B at [0,6800)
#define VTSZ   3072      // VT: 48 rows x 32 halves (one a-half at a time)
#define OFF_GM 9872      // gm f16 x 128 = 256 B at [9872,10128)
#define SLICE  10240     // per-sample LDS slice; desc overlay [0,10240) after chain1
#define WPB    4         // samples (waves) per WG; 4*10240 = 40960 B/WG
                         // -> 163840/40960 = 4 WGs/CU = 16 waves/CU using only
                         // 4 WG-slots (R4 evidence: HW caps ~8 WG-slots/CU)

#define NSET_C 48        // C-matrix frag sets: 16 nt x 3 ks
#define NSET_W 60        // W frag sets: 4 i x 5 tiles x 3 ks
#define WS_BYTES ((NSET_C + NSET_W) * 64 * 8 * 2)

// Same-wave LDS ordering fences (replace __syncthreads; R3 lesson):
// - LDS_ORDER: compiler-level memory scheduling barrier (free) -- forces
//   program order of DS instructions; HW processes a wave's DS ops in order.
// - LDS_DRAIN: additionally drains lgkmcnt at the big phase boundaries.
#define LDS_ORDER() asm volatile("" ::: "memory")
#define LDS_DRAIN() asm volatile("s_waitcnt lgkmcnt(0)" ::: "memory")

typedef _Float16 half8 __attribute__((ext_vector_type(8)));
typedef float f32x4 __attribute__((ext_vector_type(4)));

// ---- prep: constant C-matrix frags + W frags in d_ws (unchanged, verified) ----
__global__ __launch_bounds__(64) void prep_frags(const float* __restrict__ Wc,
                                                 const float* __restrict__ sig_th,
                                                 _Float16* __restrict__ ws) {
    const int blk  = blockIdx.x;
    const int lane = threadIdx.x;
    constexpr float TWO_PI = 6.28318530717958647692f;
    constexpr float DLT    = TWO_PI / 16.0f;
    constexpr float LN2    = 0.69314718055994530942f;
    half8 h;
    if (blk < NSET_C) {
        constexpr float LOG2E = 1.44269504088896340736f;
        constexpr float EPSF  = 1e-5f;
        const float st = sig_th[0];
        const float Kt = -LOG2E / (st * st + EPSF);
        const int ks = blk % 3;
        const int nt = blk / 3;
        const int t  = lane & 15;
        const int q  = lane >> 4;
        #pragma unroll
        for (int j = 0; j < 8; ++j) {
            const int k = ks * 32 + q * 8 + j;     // 0..95
            const int a = k / NDEG;
            const int d = k % NDEG;
            const int m = ((a + nt) & 15) - t;
            const float s = fmaf((float)m, DLT, 0.5f * DLT);
            const float z = 2.0f * LN2 * Kt * s * (0.5f * DLT);
            float val = exp2f(Kt * s * s);
            for (int dd = 1; dd <= d; ++dd) val *= z / (float)dd;
            h[j] = (_Float16)val;
        }
    } else {
        const int e    = blk - NSET_C;
        const int ks   = e % 3;
        const int tile = (e / 3) % 5;
        const int i    = e / 15;
        const int cc   = tile * 16 + (lane & 15);
        const int bb0  = ks * 32 + (lane >> 4) * 8;
        #pragma unroll
        for (int j = 0; j < 8; ++j) {
            const int bb = bb0 + j;
            h[j] = (_Float16)((bb < NBINS) ? Wc[i * NBINS * NBINS + bb * NBINS + cc] : 0.0f);
        }
    }
    *(half8*)(ws + ((size_t)blk * 64 + lane) * 8) = h;
}

// WAVE-PER-SAMPLE, 4 samples per 256-thread WG (R7): each 64-lane wave runs
// one full sample pipeline in its own 10240 B LDS slice -- ZERO barriers,
// all hazards same-wave DS ordering via LDS_ORDER/LDS_DRAIN (R3 lesson).
// R7 changes: (1) 4-wave WGs -> 16 waves/CU in 4 WG-slots (R4 showed a ~8
// WG-slot/CU cap defeats 1-wave WGs); (2) chain1 software-pipelined: chunk
// ch+1's A-frags + vert data prefetched at top of chunk ch (P region is
// immutable during chain1 -> safe; hides the per-chunk LDS round trip);
// (3) s_setprio(1) around MFMA clusters (waves phase-staggered, T5).
template <int USEWS>
__global__ __launch_bounds__(256, 4) void masif_geo_conv(
    const float* __restrict__ rho_c,
    const float* __restrict__ th_c,
    const float* __restrict__ feat_g,
    const float* __restrict__ mask_g,
    const float* __restrict__ mu_rho,
    const float* __restrict__ sig_rho,
    const float* __restrict__ mu_th,
    const float* __restrict__ sig_th,
    const float* __restrict__ Wc,
    const float* __restrict__ bcv,
    const _Float16* __restrict__ ws,
    const int nsamp,
    float* __restrict__ out)
{
    const int wave = threadIdx.x >> 6;
    const int lane = threadIdx.x & 63;
    const int n    = blockIdx.x * WPB + wave; // one sample per wave

    __shared__ __align__(16) char s_raw[WPB * SLICE];

    if (n >= nsamp) return;                   // safe: no barriers anywhere

    const int t  = lane & 15;
    const int kq = lane >> 4;

    char* s_base = s_raw + wave * SLICE;      // private per-wave slice
    _Float16* s_PM = (_Float16*)(s_base);                 // P, then M
    _Float16* s_vt = (_Float16*)(s_base + OFF_VT);        // VT (one col-half)
    _Float16* s_gm = (_Float16*)(s_base + OFF_GM);
    _Float16* s_d  = (_Float16*)(s_base);                 // desc overlay (late)

    constexpr float LOG2E   = 1.44269504088896340736f;
    constexpr float TWO_PI  = 6.28318530717958647692f;
    constexpr float DLT     = TWO_PI / 16.0f;
    constexpr float INV_DLT = 16.0f / TWO_PI;
    constexpr float EPSF    = 1e-5f;

    const float st = sig_th[0];
    const float Kt = -LOG2E / (st * st + EPSF);
    const float sr = sig_rho[0];
    const float Kr = -LOG2E / (sr * sr + EPSF);
    float mr[NRH];
    #pragma unroll
    for (int r = 0; r < NRH; ++r) mr[r] = mu_rho[r * 16];

    // ---- zero P incl. pads (425 int4, 64 lanes -> 7 rounds) ----
    #pragma unroll
    for (int x = 0; x < 7; ++x) {
        const int idx = x * 64 + lane;
        if (idx < 425) ((int4*)s_PM)[idx] = make_int4(0, 0, 0, 0);
    }
    LDS_ORDER();                                  // [1] zero before compaction

    // ---- compaction: 128 verts in 2 rounds of 64, wave-local ballot ----
    int nc = 0;
    #pragma unroll
    for (int h = 0; h < 2; ++h) {
        const int v     = h * 64 + lane;
        const float mv   = mask_g[n * NVERT + v];
        const float thv  = th_c[n * NVERT + v];
        const float rhov = rho_c[n * NVERT + v];
        const float4 f4  = *(const float4*)&feat_g[(n * NVERT + v) * 4];
        const bool act = (mv != 0.0f);
        const unsigned long long bal = __ballot(act);
        if (act) {
            const int pos = nc + (int)__popcll(bal & ((1ull << lane) - 1ull));
            int aa = (int)floorf(thv * INV_DLT);
            aa = aa > 15 ? 15 : (aa < 0 ? 0 : aa);
            const float rvp = thv - (float)aa * DLT - 0.5f * DLT;   // [-DLT/2, DLT/2)
            float R[NRH];
            #pragma unroll
            for (int r = 0; r < NRH; ++r) {
                const float dr = rhov - mr[r];
                R[r] = mv * exp2f(Kr * dr * dr);
            }
            const float fv[4] = {f4.x, f4.y, f4.z, f4.w};
            #pragma unroll
            for (int f = 0; f < 4; ++f) {
                #pragma unroll
                for (int r = 0; r < 4; ++r)
                    s_PM[(f * 4 + r) * PSTR + pos] = (_Float16)(fv[f] * R[r]);
                s_PM[(16 + f) * PSTR + pos] = (_Float16)(fv[f] * R[4]);
            }
            #pragma unroll
            for (int r = 0; r < NRH; ++r)
                s_PM[(20 + r) * PSTR + pos] = (_Float16)R[r];
            s_PM[(pos >> 3) * PSTR + 128 + (pos & 7)] = (_Float16)(rvp * (2.0f * INV_DLT));
            ((char*)s_PM)[(16 + (pos >> 4)) * 2 * PSTR + 256 + (pos & 15)] = (char)aa;
            s_gm[pos] = (_Float16)exp2f(Kt * rvp * rvp);
        }
        nc += (int)__popcll(bal);
    }
    LDS_DRAIN();                                  // [2] P/gm/tails complete

    // ---- chain 1: whole M (both tiles), software-pipelined chunks.
    //      Preload chunk 0's A-frags + vert data; inside chunk ch, prefetch
    //      chunk ch+1 (P region immutable during chain1 -> safe to hoist).
    //      Per chalf: zero VT, guarded 3-store, 3 b128 reads, 6 MFMAs. ----
    f32x4 M0[6], M1[6];
    #pragma unroll
    for (int cb = 0; cb < 6; ++cb) {
        M0[cb] = (f32x4){0.f, 0.f, 0.f, 0.f};
        M1[cb] = (f32x4){0.f, 0.f, 0.f, 0.f};
    }
    const int nch = (nc + 31) >> 5;
    const int cl = lane >> 1;
    const int dh = (lane & 1) * 3;
    // preload chunk 0
    half8 av0 = *(const half8*)(s_PM + t * PSTR + kq * 8);
    half8 av1 = *(const half8*)(s_PM + (16 + t) * PSTR + kq * 8);
    int   va  = (int)((char*)s_PM)[(16 + (cl >> 4)) * 2 * PSTR + 256 + (cl & 15)];
    float vu  = (float)s_PM[(cl >> 3) * PSTR + 128 + (cl & 7)];
    float vg  = (float)s_gm[cl];
    #pragma unroll 1
    for (int ch = 0; ch < nch; ++ch) {
        const bool valid = (ch * 32 + cl) < nc;
        // derive weights for current chunk from registers
        float p0, p1, p2;
        if (dh == 0) { p0 = 1.0f; p1 = vu; p2 = vu * vu; }
        else { const float u2 = vu * vu; p0 = u2 * vu; p1 = u2 * u2; p2 = p0 * u2; }
        const _Float16 w0 = (_Float16)(vg * p0);
        const _Float16 w1 = (_Float16)(vg * p1);
        const _Float16 w2 = (_Float16)(vg * p2);
        const int ah  = va >> 3;                 // col-half this vert belongs to
        const int bi0 = ((va & 7) * NDEG + dh) * VSTR + cl;
        // prefetch chunk ch+1 (clamped; garbage beyond nc is masked next iter)
        const int chn = (ch + 1 < nch) ? (ch + 1) : ch;
        const int cgn = chn * 32 + cl;
        const half8 av0n = *(const half8*)(s_PM + t * PSTR + chn * 32 + kq * 8);
        const half8 av1n = *(const half8*)(s_PM + (16 + t) * PSTR + chn * 32 + kq * 8);
        const int   van  = (int)((char*)s_PM)[(16 + (cgn >> 4)) * 2 * PSTR + 256 + (cgn & 15)];
        const float vun  = (float)s_PM[(cgn >> 3) * PSTR + 128 + (cgn & 7)];
        const float vgn  = (float)s_gm[cgn];
        #pragma unroll
        for (int chalf = 0; chalf < 2; ++chalf) {
            LDS_ORDER();                  // prev col-half's VT reads before re-zero
            #pragma unroll
            for (int x = 0; x < 3; ++x)
                ((int4*)s_vt)[x * 64 + lane] = make_int4(0, 0, 0, 0);
            LDS_ORDER();                  // zero before scatter-build
            if (valid && ah == chalf) {
                s_vt[bi0]            = w0;
                s_vt[bi0 + VSTR]     = w1;
                s_vt[bi0 + 2 * VSTR] = w2;
            }
            LDS_ORDER();                  // build before fragment reads
            // tile1 t>8 reads rows 25..31 (in-slice garbage -> unread M rows)
            #pragma unroll
            for (int lct = 0; lct < 3; ++lct) {
                const half8 b = *(const half8*)(s_vt + (lct * 16 + t) * VSTR + kq * 8);
                __builtin_amdgcn_s_setprio(1);
                M0[chalf * 3 + lct] = __builtin_amdgcn_mfma_f32_16x16x32_f16(av0, b, M0[chalf * 3 + lct], 0, 0, 0);
                M1[chalf * 3 + lct] = __builtin_amdgcn_mfma_f32_16x16x32_f16(av1, b, M1[chalf * 3 + lct], 0, 0, 0);
                __builtin_amdgcn_s_setprio(0);
            }
        }
        av0 = av0n; av1 = av1n; va = van; vu = vun; vg = vgn;
    }
    LDS_ORDER();                                  // chain1 reads before M overwrite

    // ---- M (both tiles) -> LDS f16 A-layout. D: col=t, row=kq*4+reg ----
    #pragma unroll
    for (int cb = 0; cb < 6; ++cb) {
        const int md = cb * 16 + t;
        #pragma unroll
        for (int reg = 0; reg < 4; ++reg) {
            const int lr = kq * 4 + reg;
            s_PM[lr * PSTR + md] = (_Float16)M0[cb][reg];
            if (lr < 9)
                s_PM[(16 + lr) * PSTR + md] = (_Float16)M1[cb][reg];
        }
    }
    LDS_DRAIN();                                  // [3] M complete before A-frag reads

    // ---- chain2 A-frags -> regs (before desc overlays P/M) ----
    half8 A0[3], A1[3];
    #pragma unroll
    for (int ks = 0; ks < 3; ++ks) {
        A0[ks] = *(const half8*)(s_PM + t * PSTR + ks * 32 + kq * 8);
        A1[ks] = *(const half8*)(s_PM + (16 + t) * PSTR + ks * 32 + kq * 8);
    }
    LDS_ORDER();                                  // [4] A-frag reads before desc overlay

    // ---- chain 2: g-loop, unroll 2 so next g's ws loads pipeline under
    //      this g's MFMAs+epilogue; fused epilogue ----
    const half8* wsv = (const half8*)ws;
    #pragma unroll 2
    for (int g = 0; g < 4; ++g) {
        f32x4 C0g[4], C1g[4];
        #pragma unroll
        for (int j = 0; j < 4; ++j) {
            C0g[j] = (f32x4){0.f, 0.f, 0.f, 0.f};
            C1g[j] = (f32x4){0.f, 0.f, 0.f, 0.f};
        }
        #pragma unroll
        for (int j = 0; j < 4; ++j) {
            const int nt = g * 4 + j;
            half8 b0, b1, b2;
            if (USEWS) {
                b0 = wsv[(size_t)((nt * 3 + 0) * 64 + lane)];
                b1 = wsv[(size_t)((nt * 3 + 1) * 64 + lane)];
                b2 = wsv[(size_t)((nt * 3 + 2) * 64 + lane)];
            } else {
                #pragma unroll
                for (int ks = 0; ks < 3; ++ks) {
                    half8 bb;
                    #pragma unroll
                    for (int jj = 0; jj < 8; ++jj) {
                        const int k = ks * 32 + kq * 8 + jj;
                        const int a = k / NDEG, d = k % NDEG;
                        const int mm = ((a + nt) & 15) - t;
                        const float s = fmaf((float)mm, DLT, 0.5f * DLT);
                        const float z = 2.0f * 0.69314718055994530942f * Kt * s * (0.5f * DLT);
                        float val = exp2f(Kt * s * s);
                        for (int dd = 1; dd <= d; ++dd) val *= z / (float)dd;
                        bb[jj] = (_Float16)val;
                    }
                    if (ks == 0) b0 = bb; else if (ks == 1) b1 = bb; else b2 = bb;
                }
            }
            __builtin_amdgcn_s_setprio(1);
            C0g[j] = __builtin_amdgcn_mfma_f32_16x16x32_f16(A0[0], b0, C0g[j], 0, 0, 0);
            C1g[j] = __builtin_amdgcn_mfma_f32_16x16x32_f16(A1[0], b0, C1g[j], 0, 0, 0);
            C0g[j] = __builtin_amdgcn_mfma_f32_16x16x32_f16(A0[1], b1, C0g[j], 0, 0, 0);
            C1g[j] = __builtin_amdgcn_mfma_f32_16x16x32_f16(A1[1], b1, C1g[j], 0, 0, 0);
            C0g[j] = __builtin_amdgcn_mfma_f32_16x16x32_f16(A0[2], b2, C0g[j], 0, 0, 0);
            C1g[j] = __builtin_amdgcn_mfma_f32_16x16x32_f16(A1[2], b2, C1g[j], 0, 0, 0);
            __builtin_amdgcn_s_setprio(0);
        }
        // fused epilogue: desc = num/(den+eps) -> s_d[i][nt][bb]
        #pragma unroll
        for (int j = 0; j < 4; ++j) {
            const int nt = g * 4 + j;
            float den[5], inv[5];
            #pragma unroll
            for (int r = 0; r < 4; ++r) den[r] = __shfl(C1g[j][r], 16 + t);
            den[4] = __shfl(C1g[j][0], 32 + t);
            #pragma unroll
            for (int r = 0; r < NRH; ++r) {
                const float x = den[r] + EPSF;
                float vv = __builtin_amdgcn_rcpf(x);
                inv[r] = vv * (2.0f - x * vv);
            }
            #pragma unroll
            for (int reg = 0; reg < 4; ++reg)
                s_d[kq * DI + nt * DSTR + reg * 16 + t] =
                    (_Float16)(C0g[j][reg] * inv[reg]);
            if (kq == 0) {
                #pragma unroll
                for (int reg = 0; reg < 4; ++reg)
                    s_d[reg * DI + nt * DSTR + 64 + t] =
                        (_Float16)(C1g[j][reg] * inv[4]);
            }
        }
    }
    LDS_DRAIN();                                  // [5] desc complete before phase2 reads

    // ---- phase 2: i-loop, unroll 2 (pipeline W/desc loads across i) ----
    #pragma unroll 2
    for (int i = 0; i < 4; ++i) {
        f32x4 Cc[5];
        #pragma unroll
        for (int tl = 0; tl < 5; ++tl) Cc[tl] = (f32x4){0.f, 0.f, 0.f, 0.f};
        #pragma unroll
        for (int ks = 0; ks < 3; ++ks) {
            const half8 a = *(const half8*)(s_d + i * DI + t * DSTR + ks * 32 + kq * 8);
            half8 b[5];
            #pragma unroll
            for (int tl = 0; tl < 5; ++tl) {
                if (USEWS) {
                    b[tl] = wsv[(size_t)((NSET_C + (i * 5 + tl) * 3 + ks) * 64 + lane)];
                } else {
                    const int cc  = tl * 16 + t;
                    const int bb0 = ks * 32 + kq * 8;
                    #pragma unroll
                    for (int j = 0; j < 8; ++j) {
                        const int bb = bb0 + j;
                        b[tl][j] = (_Float16)((bb < NBINS) ? Wc[i * NBINS * NBINS + bb * NBINS + cc] : 0.0f);
                    }
                }
            }
            __builtin_amdgcn_s_setprio(1);
            #pragma unroll
            for (int tl = 0; tl < 5; ++tl)
                Cc[tl] = __builtin_amdgcn_mfma_f32_16x16x32_f16(a, b[tl], Cc[tl], 0, 0, 0);
            __builtin_amdgcn_s_setprio(0);
        }
        #pragma unroll
        for (int tl = 0; tl < 5; ++tl) {
            float mx = fmaxf(fmaxf(Cc[tl][0], Cc[tl][1]), fmaxf(Cc[tl][2], Cc[tl][3]));
            mx = fmaxf(mx, __shfl_xor(mx, 16));
            mx = fmaxf(mx, __shfl_xor(mx, 32));
            if (lane < 16) {
                const int cc = tl * 16 + lane;
                out[(size_t)n * 320 + i * NBINS + cc] =
                    fmaxf(mx + bcv[i * NBINS + cc], 0.0f);
            }
        }
    }
}

extern "C" void kernel_launch(void* const* d_in, const int* in_sizes, int n_in,
                              void* d_out, int out_size, void* d_ws, size_t ws_size,
                              hipStream_t stream) {
    const float* rho   = (const float*)d_in[0];
    const float* theta = (const float*)d_in[1];
    const float* feat  = (const float*)d_in[2];
    const float* mask  = (const float*)d_in[3];
    const float* mu_r  = (const float*)d_in[4];
    const float* sg_r  = (const float*)d_in[5];
    const float* mu_t  = (const float*)d_in[6];
    const float* sg_t  = (const float*)d_in[7];
    const float* W     = (const float*)d_in[8];
    const float* bconv = (const float*)d_in[9];
    float* outp = (float*)d_out;

    const int nsamp = in_sizes[0] / NVERT;
    const int ngrid = (nsamp + WPB - 1) / WPB;    // 4 samples per WG
    const int useWs = (ws_size >= (size_t)WS_BYTES) ? 1 : 0;
    _Float16* wsh = (_Float16*)d_ws;

    if (useWs) {
        prep_frags<<<NSET_C + NSET_W, 64, 0, stream>>>(W, sg_t, wsh);
        masif_geo_conv<1><<<ngrid, 64 * WPB, 0, stream>>>(
            rho, theta, feat, mask, mu_r, sg_r, mu_t, sg_t, W, bconv,
            wsh, nsamp, outp);
    } else {
        masif_geo_conv<0><<<ngrid, 64 * WPB, 0, stream>>>(
            rho, theta, feat, mask, mu_r, sg_r, mu_t, sg_t, W, bconv,
            wsh, nsamp, outp);
    }
}